// Round 7
// baseline (331.449 us; speedup 1.0000x reference)
//
#include <hip/hip_runtime.h>
#include <hip/hip_bf16.h>

// MoE top-2, d=1024, E=8, N=8192 tokens. Grouped-GEMM design:
//   gate(top2 + x->bf16 cast + zeroing) -> fillplan -> GEMM1(relu) -> GEMM2(+atomic combine)
// R4-R8: all in-block schedule knobs null; perf tracks LDS-capped residency:
//   128KB->1 blk/CU->163us; 64KB->2->130; 48KB->3->113. TLP is the lever (m114/m97).
// R9: 128x64 tile (24KB LDS) + __launch_bounds__(256,4) -> hard crash. Audit: all
//   offsets in-range; prime suspect = forced 128-reg cap -> spill -> scratch+graph abort.
// R10: R6 gemm + fused infra + hierarchical fillplan = 325us (passed, banked).
// R11: R9's 128x64 k_gemm WITHOUT the forced launch bound (natural ~110 unified regs
//   -> 4 waves/SIMD; LDS 24KB -> 6 blocks) -> expect 4+ blocks/CU residency.
//   Everything else identical to R10. Grid 2176 = 16 col x 136 row, XCD-swizzled.

#define NTOK   8192
#define DM     1024
#define NE     8
#define BM     128
#define NSLOT  (NTOK * 2)
#define PADCAP (NSLOT + NE * BM)      // 17408
#define MAXTILES (PADCAP / BM)        // 136

typedef __attribute__((ext_vector_type(8))) short  bf16x8;
typedef __attribute__((ext_vector_type(4))) float  f32x4;
typedef __attribute__((ext_vector_type(8))) unsigned short u16x8;

__device__ __forceinline__ unsigned short f2bf(float f) {
    union { float f; unsigned u; } v; v.f = f;
    unsigned r = v.u + 0x7fffu + ((v.u >> 16) & 1u);
    return (unsigned short)(r >> 16);
}

// async global->LDS DMA, 16B per lane; dest = wave-uniform base + lane*16
__device__ __forceinline__ void load_lds16(const ushort* g, ushort* l) {
    __builtin_amdgcn_global_load_lds(
        (const __attribute__((address_space(1))) unsigned int*)g,
        (__attribute__((address_space(3))) unsigned int*)l,
        16, 0, 0);
}

// ---------- transpose + cast both weight tensors: Wt[e][n][k] = W[e][k][n] ----------
// Also zeroes counts/cursor (runs first on the stream; k_gate depends on it).
__global__ __launch_bounds__(256) void k_transpose2(const float* __restrict__ W1,
                                                    const float* __restrict__ W2,
                                                    ushort* __restrict__ w1t,
                                                    ushort* __restrict__ w2t,
                                                    int* __restrict__ counts) {
    int tid = threadIdx.x;
    if (blockIdx.x == 0 && blockIdx.y == 0 && blockIdx.z == 0 && tid < 16)
        counts[tid] = 0;   // counts[0..7] + cursor[0..7]
    int ez = blockIdx.z;
    const float* W = (ez < 8 ? W1 : W2) + (size_t)(ez & 7) * DM * DM;
    ushort* Wt = (ez < 8 ? w1t : w2t) + (size_t)(ez & 7) * DM * DM;
    __shared__ float t[64][65];
    int kt = blockIdx.y * 64, nt = blockIdx.x * 64;
    int r16 = tid >> 4, c4 = (tid & 15) * 4;
#pragma unroll
    for (int p = 0; p < 4; p++) {
        int k = p * 16 + r16;
        float4 v = *(const float4*)&W[(size_t)(kt + k) * DM + nt + c4];
        t[k][c4] = v.x; t[k][c4 + 1] = v.y; t[k][c4 + 2] = v.z; t[k][c4 + 3] = v.w;
    }
    __syncthreads();
    int n = tid >> 2, kb = (tid & 3) * 16;
#pragma unroll
    for (int h = 0; h < 2; h++) {
        int k0 = kb + h * 8;
        u16x8 o;
#pragma unroll
        for (int i = 0; i < 8; i++) o[i] = f2bf(t[k0 + i][n]);
        *(u16x8*)&Wt[(size_t)(nt + n) * DM + kt + k0] = o;
    }
}

// ---------- gating: scores = x@Wg + bg (fp32 exact), top-2, counts; casts x->bf16 ----------
// Also zeroes its 16 output rows and its slot_token chunk (replaces memset launches).
__global__ __launch_bounds__(256) void k_gate(const float* __restrict__ x,
                                              const float* __restrict__ Wg,
                                              const float* __restrict__ bg,
                                              ushort* __restrict__ xb,
                                              int* __restrict__ tok_e,
                                              float* __restrict__ tok_w,
                                              int* __restrict__ counts,
                                              float* __restrict__ out,
                                              int* __restrict__ slot_token) {
    __shared__ float wgT[NE][DM];   // 32 KB, transposed: wgT[e][d] = Wg[d][e]
    __shared__ int cnt[NE];
    int tid = threadIdx.x;
    if (tid < NE) cnt[tid] = 0;
    // zero out rows [16*blk, 16*blk+16): 4096 float4 across 256 threads
    {
        float4 z4 = {0.f, 0.f, 0.f, 0.f};
        float4* orow = (float4*)(out + (size_t)blockIdx.x * 16 * DM);
#pragma unroll
        for (int i = 0; i < 16; i++) orow[i * 256 + tid] = z4;
        // slot_token sentinels: PADCAP = 512 blocks * 34
        int s0 = blockIdx.x * (PADCAP / 512);
        for (int i = tid; i < PADCAP / 512; i += 256) slot_token[s0 + i] = -1;
    }
    for (int i = tid; i < DM * NE; i += 256) {
        int d = i >> 3, e = i & 7;
        wgT[e][d] = Wg[i];
    }
    __syncthreads();
    int wave = tid >> 6, lane = tid & 63;
    int n0 = (blockIdx.x * 4 + wave) * 4;
    const float4* xr[4];
#pragma unroll
    for (int t = 0; t < 4; t++) xr[t] = (const float4*)(x + (size_t)(n0 + t) * DM);

    float acc[4][NE];
#pragma unroll
    for (int t = 0; t < 4; t++)
#pragma unroll
        for (int e = 0; e < NE; e++) acc[t][e] = 0.f;

#pragma unroll
    for (int j = 0; j < 4; j++) {
        float4 xv[4];
#pragma unroll
        for (int t = 0; t < 4; t++) xv[t] = xr[t][j * 64 + lane];
#pragma unroll
        for (int t = 0; t < 4; t++) {
            ushort4 o;
            o.x = f2bf(xv[t].x); o.y = f2bf(xv[t].y);
            o.z = f2bf(xv[t].z); o.w = f2bf(xv[t].w);
            ((ushort4*)xb)[(size_t)(n0 + t) * (DM / 4) + j * 64 + lane] = o;
        }
#pragma unroll
        for (int e = 0; e < NE; e++) {
            float4 wv = ((const float4*)&wgT[e][0])[j * 64 + lane];
#pragma unroll
            for (int t = 0; t < 4; t++) {
                acc[t][e] += xv[t].x * wv.x + xv[t].y * wv.y
                           + xv[t].z * wv.z + xv[t].w * wv.w;
            }
        }
    }
#pragma unroll
    for (int t = 0; t < 4; t++)
#pragma unroll
        for (int e = 0; e < NE; e++) {
#pragma unroll
            for (int off = 32; off >= 1; off >>= 1)
                acc[t][e] += __shfl_xor(acc[t][e], off);
        }
    if (lane < 4) {
        int t = lane, n = n0 + t;
        float sc[NE];
#pragma unroll
        for (int e = 0; e < NE; e++) sc[e] = acc[t][e] + bg[e];
        int e0 = 0; float v0 = sc[0];
#pragma unroll
        for (int e = 1; e < NE; e++) if (sc[e] > v0) { v0 = sc[e]; e0 = e; }
        int e1 = -1; float v1 = -3.0e38f;
#pragma unroll
        for (int e = 0; e < NE; e++) if (e != e0 && sc[e] > v1) { v1 = sc[e]; e1 = e; }
        tok_e[2 * n] = e0;     tok_w[2 * n] = v0;
        tok_e[2 * n + 1] = e1; tok_w[2 * n + 1] = v1;
        atomicAdd(&cnt[e0], 1);
        atomicAdd(&cnt[e1], 1);
    }
    __syncthreads();
    if (tid < NE) atomicAdd(&counts[tid], cnt[tid]);
}

// ---------- fill + plan merged, hierarchical atomics ----------
// Per-block LDS counts -> 8 global atomicAdds/block (vs 512) -> local scatter.
// Range-proof: p0/p1 < lcnt[e] <= 256; sum over blocks of lcnt = counts[e];
// s = base[e] + lbase[e] + p < base[e] + counts[e] <= PADCAP.
__global__ __launch_bounds__(256) void k_fillplan(const int* __restrict__ tok_e,
                                                  const float* __restrict__ tok_w,
                                                  const int* __restrict__ counts,
                                                  int* __restrict__ cursor,
                                                  int* __restrict__ slot_token,
                                                  float* __restrict__ slot_w,
                                                  int* __restrict__ tile_e,
                                                  int* __restrict__ tile_b,
                                                  int* __restrict__ ntiles) {
    __shared__ int lcnt[NE], lbase[NE];
    int tid = threadIdx.x;
    if (tid < NE) lcnt[tid] = 0;
    __syncthreads();
    int n = blockIdx.x * 256 + tid;
    int e0 = tok_e[2 * n],     e1 = tok_e[2 * n + 1];
    float w0 = tok_w[2 * n],   w1 = tok_w[2 * n + 1];
    int p0 = atomicAdd(&lcnt[e0], 1);
    int p1 = atomicAdd(&lcnt[e1], 1);
    __syncthreads();
    if (tid < NE) lbase[tid] = atomicAdd(&cursor[tid], lcnt[tid]);
    if (blockIdx.x == 0 && tid == 32) {   // different wave than the cursor atomics
        int t = 0, o2 = 0;
        for (int e = 0; e < NE; e++) {
            int nt = (counts[e] + BM - 1) / BM;
            for (int i = 0; i < nt; i++) { tile_e[t] = e; tile_b[t] = o2 + i * BM; t++; }
            o2 += nt * BM;
        }
        *ntiles = t;
    }
    __syncthreads();
    int base[NE]; int off = 0;
#pragma unroll
    for (int e = 0; e < NE; e++) {
        base[e] = off;
        off += ((counts[e] + BM - 1) / BM) * BM;
    }
    int s0 = base[e0] + lbase[e0] + p0;
    slot_token[s0] = n; slot_w[s0] = w0;
    int s1 = base[e1] + lbase[e1] + p1;
    slot_token[s1] = n; slot_w[s1] = w1;
}

// ---------- grouped GEMM: 128x64 tile, BK=32, double-buffered async pipeline ----------
// TLP-first: 4 waves, acc 4x2 f32x4 (32 AGPR) + ~75 VGPR, NATURAL allocation
// (no forced min-waves; R9's (256,4) cap is the suspected crash cause).
// LDS: A 128x32 (8KB) + B 64x32 (4KB), x2 bufs = 24 KB -> 6 blocks/CU by LDS;
// regs ~110 unified -> 4 waves/SIMD -> expect ~4 blocks/CU resident.
// Staging (R4-proven 4-seg xor): chunk = 16 rows x 64B; lane l -> row c*16+(l>>2),
//   LDS seg l&3, GLOBAL seg (l&3)^((l>>4)&3). Wave w: A chunks {2w,2w+1}, B chunk w
//   -> 3 DMA/iter/wave. Fragment sel = (quad^(lm>>2))&3 -> conflict-free ds_read_b128.
// Pipeline: prefetch next buf, s_waitcnt vmcnt(3) (current buf's 3 done, 3 in flight),
//   raw s_barrier; R6 fences: sched_barrier(0) around COMPUTE + lgkmcnt(0) before
//   the end barrier. Grid 2176 = 16 col x 136 row tiles, XCD-swizzled (272/XCD).
template <int PHASE>
__global__ __launch_bounds__(256) void k_gemm(const ushort* __restrict__ A,
                                              const ushort* __restrict__ Wt,
                                              const float* __restrict__ bias,
                                              const int* __restrict__ slot_token,
                                              const float* __restrict__ slot_w,
                                              const int* __restrict__ tile_e,
                                              const int* __restrict__ tile_b,
                                              const int* __restrict__ ntiles,
                                              ushort* __restrict__ Hout,
                                              float* __restrict__ out) {
    int flat = blockIdx.x;
    int wid = (flat & 7) * (MAXTILES * 2) + (flat >> 3);   // 2176/8 = 272 per XCD
    int t = wid >> 4;
    if (t >= *ntiles) return;
    int ncol0 = (wid & 15) << 6;
    int e = tile_e[t];
    int sbase = tile_b[t];

    __shared__ ushort As[2][4096];   // [buf][row*32 + segpos*8], 128 rows
    __shared__ ushort Bs[2][2048];   // [buf][row*32 + segpos*8],  64 rows

    int tid = threadIdx.x;
    int wave = tid >> 6, lane = tid & 63, quad = lane >> 4, lm = lane & 15;
    int wm = wave >> 1, wn = wave & 1;

    const ushort* Wte = Wt + (size_t)e * DM * DM;

    int sr = lane >> 2;                            // row-in-chunk 0..15
    int gseg = (lane & 3) ^ ((lane >> 4) & 3);     // global 16B-seg (xor swizzle)
    const ushort* aptr[2];
    const ushort* bptr;
#pragma unroll
    for (int ci = 0; ci < 2; ci++) {
        int row = (wave * 2 + ci) * 16 + sr;
        int ar;
        if (PHASE == 1) {
            ar = slot_token[sbase + row];
            if (ar < 0) ar = 0;              // pad rows: load row 0, discard in epilogue
        } else {
            ar = sbase + row;
        }
        aptr[ci] = A + (size_t)ar * DM + gseg * 8;
    }
    {
        int brow = wave * 16 + sr;
        bptr = Wte + (size_t)(ncol0 + brow) * DM + gseg * 8;
    }

    f32x4 acc[4][2];
#pragma unroll
    for (int i = 0; i < 4; i++)
#pragma unroll
        for (int j = 0; j < 2; j++) acc[i][j] = (f32x4){0.f, 0.f, 0.f, 0.f};

    // fragment LDS offsets (ushort units): lane-constant swizzle sel
    int asel = ((quad ^ (lm >> 2)) & 3) * 8;
    int abase = (wm * 64 + lm) * 32 + asel;
    int bbase = (wn * 32 + lm) * 32 + asel;

#define ISSUE(buf, koff)                                              \
    do {                                                              \
        load_lds16(aptr[0] + (koff), &As[(buf)][(wave * 2 + 0) * 512]); \
        load_lds16(aptr[1] + (koff), &As[(buf)][(wave * 2 + 1) * 512]); \
        load_lds16(bptr + (koff), &Bs[(buf)][wave * 512]);            \
    } while (0)

#define COMPUTE(buf)                                                          \
    do {                                                                      \
        const ushort* Ab = As[(buf)];                                         \
        const ushort* Bb = Bs[(buf)];                                         \
        bf16x8 av[4], bv[2];                                                  \
        _Pragma("unroll")                                                     \
        for (int f = 0; f < 4; f++) av[f] = *(const bf16x8*)&Ab[abase + f * 512]; \
        _Pragma("unroll")                                                     \
        for (int f = 0; f < 2; f++) bv[f] = *(const bf16x8*)&Bb[bbase + f * 512]; \
        __builtin_amdgcn_s_setprio(1);                                        \
        _Pragma("unroll")                                                     \
        for (int fm = 0; fm < 4; fm++)                                        \
            _Pragma("unroll")                                                 \
            for (int fn = 0; fn < 2; fn++)                                    \
                acc[fm][fn] = __builtin_amdgcn_mfma_f32_16x16x32_bf16(        \
                    av[fm], bv[fn], acc[fm][fn], 0, 0, 0);                    \
        __builtin_amdgcn_s_setprio(0);                                        \
    } while (0)

    ISSUE(0, 0);
#pragma unroll 2
    for (int it = 0; it < 32; ++it) {
        if (it < 31) {
            ISSUE((it + 1) & 1, (it + 1) * 32);
            __builtin_amdgcn_s_waitcnt(0x0F73);   // vmcnt(3): current buf's 3 done
        } else {
            __builtin_amdgcn_s_waitcnt(0x0F70);   // vmcnt(0): last buf done
        }
        __builtin_amdgcn_s_barrier();
        __builtin_amdgcn_sched_barrier(0);        // ds_reads may not hoist above
        COMPUTE(it & 1);
        __builtin_amdgcn_sched_barrier(0);        // nothing sinks below
        __builtin_amdgcn_s_waitcnt(0xC07F);       // lgkmcnt(0): ds_reads retired
        __builtin_amdgcn_s_barrier();             // readers done before buf re-staged
    }
#undef ISSUE
#undef COMPUTE

    // epilogue — C/D layout: col = lane&15, row = quad*4 + r  [m89-verified]
#pragma unroll
    for (int fm = 0; fm < 4; fm++) {
        int rowg = wm * 64 + fm * 16 + quad * 4;
        if (PHASE == 1) {
#pragma unroll
            for (int fn = 0; fn < 2; fn++) {
                int col = ncol0 + wn * 32 + fn * 16 + lm;
                float bv2 = bias[e * DM + col];
#pragma unroll
                for (int r = 0; r < 4; r++) {
                    float v = acc[fm][fn][r] + bv2;
                    v = fmaxf(v, 0.f);
                    Hout[(size_t)(sbase + rowg + r) * DM + col] = f2bf(v);
                }
            }
        } else {
            int tk[4]; float wv[4];
#pragma unroll
            for (int r = 0; r < 4; r++) {
                tk[r] = slot_token[sbase + rowg + r];
                wv[r] = slot_w[sbase + rowg + r];
            }
#pragma unroll
            for (int fn = 0; fn < 2; fn++) {
                int col = ncol0 + wn * 32 + fn * 16 + lm;
                float bv2 = bias[e * DM + col];
#pragma unroll
                for (int r = 0; r < 4; r++) {
                    if (tk[r] >= 0) {
                        float v = wv[r] * (acc[fm][fn][r] + bv2);
                        atomicAdd(&out[(size_t)tk[r] * DM + col], v);
                    }
                }
            }
        }
    }
}

extern "C" void kernel_launch(void* const* d_in, const int* in_sizes, int n_in,
                              void* d_out, int out_size, void* d_ws, size_t ws_size,
                              hipStream_t stream) {
    const float* x  = (const float*)d_in[0];
    const float* Wg = (const float*)d_in[1];
    const float* bg = (const float*)d_in[2];
    const float* W1 = (const float*)d_in[3];
    const float* b1 = (const float*)d_in[4];
    const float* W2 = (const float*)d_in[5];
    const float* b2 = (const float*)d_in[6];
    float* out = (float*)d_out;

    char* ws = (char*)d_ws;
    // workspace layout (bytes) — total ~86.3 MB
    ushort* xb         = (ushort*)(ws + 0);            // 16 MB
    ushort* w1t        = (ushort*)(ws + 16777216);     // 16 MB
    ushort* w2t        = (ushort*)(ws + 33554432);     // 16 MB
    ushort* H          = (ushort*)(ws + 50331648);     // 34 MB (PADCAP*DM*2)
    int*    tok_e      = (int*)  (ws + 85983232);
    float*  tok_w      = (float*)(ws + 86048768);
    int*    slot_token = (int*)  (ws + 86114304);
    float*  slot_w     = (float*)(ws + 86183936);
    int*    counts     = (int*)  (ws + 86253568);
    int*    cursor     = counts + 8;
    int*    tile_e     = counts + 24;
    int*    tile_b     = tile_e + MAXTILES;
    int*    ntiles     = tile_b + MAXTILES;

    dim3 tg(16, 16, 16);
    k_transpose2<<<tg, 256, 0, stream>>>(W1, W2, w1t, w2t, counts);
    k_gate<<<NTOK / 16, 256, 0, stream>>>(x, Wg, bg, xb, tok_e, tok_w, counts,
                                          out, slot_token);
    k_fillplan<<<NTOK / 256, 256, 0, stream>>>(tok_e, tok_w, counts, cursor,
                                               slot_token, slot_w,
                                               tile_e, tile_b, ntiles);

    dim3 gg(16 * MAXTILES);   // 2176 blocks, XCD-swizzled in-kernel
    k_gemm<1><<<gg, 256, 0, stream>>>(xb, w1t, b1, slot_token, slot_w,
                                      tile_e, tile_b, ntiles, H, nullptr);
    k_gemm<2><<<gg, 256, 0, stream>>>(H, w2t, b2, slot_token, slot_w,
                                      tile_e, tile_b, ntiles, nullptr, out);
}